// Round 22
// baseline (48.836 us; speedup 1.0000x reference)
//
#include <hip/hip_runtime.h>

// SSIM loss, 7x7 window, VALID, (64,1,512,512) fp32.
// R22 = R20 skeleton (pk-f32 verticals, read-early dual-slot, SH=64,
// barrier-free wave strips) + f16-packed LDS staging:
//  - taps are 4B h2 -> compiler merges to ds_read2_b32: DS bytes halved
//    (DS unit is BYTE-bound per m134; R21's b128 merge saved nothing)
//  - hss/hw via fdot2 (f16 mul, f32 accumulate - no cancellation hazard)
//  - (hx,hy) via 6 v_pk_add_f16 + 2 cvt
//  - 4 vertical channels: P=(sx,sy) pk-f32, vss, vw(=2Sxy); history 28 regs
// Hard constraints learned R13/R21: VGPR <= 64 (occupancy cliff above).

constexpr int B  = 64;
constexpr int H  = 512, W = 512;
constexpr int OH = H - 6, OW = W - 6;     // 506
constexpr int CW = 64;                    // output cols per wave
constexpr int BW_ = 4 * CW;               // output cols per block (256)
constexpr int SH = 64;                    // output rows per block

typedef float  f2 __attribute__((ext_vector_type(2)));
typedef __fp16 h2 __attribute__((ext_vector_type(2)));

__global__ __launch_bounds__(256)
void ssim_main(const float* __restrict__ X, const float* __restrict__ Y,
               const float* __restrict__ DR, float* __restrict__ partials)
{
    const int tid  = threadIdx.x;
    const int wid  = tid >> 6;
    const int lane = tid & 63;
    const int c0   = blockIdx.x * BW_ + wid * CW;   // wave-private strip
    const int r0   = blockIdx.y * SH;
    const int b    = blockIdx.z;

    const int out_rows = min(SH, OH - r0);
    const int rows_in  = out_rows + 6;       // <= 70, block-uniform

    const float d  = DR[b];
    const float C1 = (0.01f * d) * (0.01f * d);
    const float C2 = (0.03f * d) * (0.03f * d);
    const float c1s = 2401.0f * C1;          // 49^2 * C1
    const float c2s = 2352.0f * C2;          // 48*49 * C2

    const float* __restrict__ Xb = X + (size_t)b * H * W;
    const float* __restrict__ Yb = Y + (size_t)b * H * W;

    unsigned off  = (unsigned)(r0 * W + c0 + lane);
    unsigned hoff = (unsigned)(r0 * W + min(c0 + CW + lane, W - 1));

    const bool colvalid = (c0 + lane) < OW;
    const bool is_halo  = lane < 6;

    // wave-private DUAL-slot row buffer: packed f16 {x,y}, 70 used per slot
    __shared__ h2 rb[4][2][CW + 8];

    // vertical state: P=(sx,sy) packed; vss=S(xx+yy); vw=2*Sxy
    f2 bP[7];
    float bhs[7], bhw[7];
    f2 P = {0.f, 0.f};
    float vss = 0.f, vw = 0.f;
#pragma unroll
    for (int i = 0; i < 7; ++i) { bP[i] = P; bhs[i] = 0.f; bhw[i] = 0.f; }

    float acc = 0.f;

    // prefetch pairs by parity: pre1 holds odd rows, pre0 even rows
    f2 pre0, pre1;
    f2 preh0 = {0.f, 0.f}, preh1 = {0.f, 0.f};

    // ---- prologue: row0 -> slot0 (staged), row1 -> pre1, row2 -> pre0 ----
    {
        f2 p0; p0.x = Xb[off]; p0.y = Yb[off];
        f2 ph0 = {0.f, 0.f};
        if (is_halo) { ph0.x = Xb[hoff]; ph0.y = Yb[hoff]; }
        off += W; hoff += W;
        pre1.x = Xb[off]; pre1.y = Yb[off];
        if (is_halo) { preh1.x = Xb[hoff]; preh1.y = Yb[hoff]; }
        off += W; hoff += W;
        pre0.x = Xb[off]; pre0.y = Yb[off];
        if (is_halo) { preh0.x = Xb[hoff]; preh0.y = Yb[hoff]; }
        off += W; hoff += W;

        h2* s0 = rb[wid][0];
        s0[lane] = __builtin_amdgcn_cvt_pkrtz(p0.x, p0.y);
        if (is_halo) s0[CW + lane] = __builtin_amdgcn_cvt_pkrtz(ph0.x, ph0.y);
    }

    for (int rr = 0; rr < 70; rr += 14) {
#pragma unroll
        for (int p = 0; p < 14; ++p) {
            const int r = rr + p;              // r%7 == p%7, r&1 == p&1
            if (r < rows_in) {                 // block-uniform
                h2* const rslot = rb[wid][p & 1];        // row r (staged)
                h2* const wslot = rb[wid][(p & 1) ^ 1];  // row r+1 dest
                f2& pr = (p & 1) ? pre0 : pre1;          // pair(r+1)
                f2& ph = (p & 1) ? preh0 : preh1;

                // 1) tap reads of row r (staged last phase; b32-class,
                //    consecutive dword offsets -> ds_read2_b32 merges)
                const h2 t0 = rslot[lane+0], t1 = rslot[lane+1],
                         t2 = rslot[lane+2], t3 = rslot[lane+3],
                         t4 = rslot[lane+4], t5 = rslot[lane+5],
                         t6 = rslot[lane+6];

                // 2) stage row r+1 into the other slot
                if (r + 1 < rows_in) {
                    wslot[lane] = __builtin_amdgcn_cvt_pkrtz(pr.x, pr.y);
                    if (is_halo) wslot[CW + lane] = __builtin_amdgcn_cvt_pkrtz(ph.x, ph.y);
                    // 3) issue globals for row r+3 (same parity regs)
                    if (r + 3 < rows_in) {
                        pr.x = Xb[off]; pr.y = Yb[off];
                        if (is_halo) { ph.x = Xb[hoff]; ph.y = Yb[hoff]; }
                        off += W; hoff += W;
                    }
                }

                // 4) compute row r
                // hss = S(x^2+y^2): f16 mul, f32 accumulate
                float hss = __builtin_amdgcn_fdot2(t0, t0, 0.f, false);
                hss = __builtin_amdgcn_fdot2(t1, t1, hss, false);
                hss = __builtin_amdgcn_fdot2(t2, t2, hss, false);
                hss = __builtin_amdgcn_fdot2(t3, t3, hss, false);
                hss = __builtin_amdgcn_fdot2(t4, t4, hss, false);
                hss = __builtin_amdgcn_fdot2(t5, t5, hss, false);
                hss = __builtin_amdgcn_fdot2(t6, t6, hss, false);

                // hw = 2*S(x*y)
                #define SW(t) __builtin_shufflevector(t, t, 1, 0)
                float hw = __builtin_amdgcn_fdot2(t0, SW(t0), 0.f, false);
                hw = __builtin_amdgcn_fdot2(t1, SW(t1), hw, false);
                hw = __builtin_amdgcn_fdot2(t2, SW(t2), hw, false);
                hw = __builtin_amdgcn_fdot2(t3, SW(t3), hw, false);
                hw = __builtin_amdgcn_fdot2(t4, SW(t4), hw, false);
                hw = __builtin_amdgcn_fdot2(t5, SW(t5), hw, false);
                hw = __builtin_amdgcn_fdot2(t6, SW(t6), hw, false);
                #undef SW

                // (hx,hy) via packed f16 adds, then widen
                const h2 hp = ((t0 + t1) + (t2 + t3)) + ((t4 + t5) + t6);
                const f2 s2 = { (float)hp.x, (float)hp.y };

                // vertical running 7-row window (slot p%7 holds row r-7)
                constexpr int s7[14] = {0,1,2,3,4,5,6,0,1,2,3,4,5,6};
                const int sp = s7[p];
                P   += s2  - bP[sp];  bP[sp]  = s2;    // 2 pk
                vss += hss - bhs[sp]; bhs[sp] = hss;
                vw  += hw  - bhw[sp]; bhw[sp] = hw;

                if (r >= 6 && colvalid) {
                    // S = (2 SxSy + c1s)(49 vw - 2 SxSy + c2s)
                    //   / (Sx^2+Sy^2+c1s)(49 vss - Sx^2 - Sy^2 + c2s)
                    const float vsx = P.x, vsy = P.y;
                    const float p1 = vsx * vsy;
                    const float u1 = fmaf(2.f, p1, c1s);
                    const float u2 = fmaf(-2.f, p1, fmaf(49.f, vw, c2s));
                    const float n2 = fmaf(vsy, vsy, vsx * vsx);
                    const float d1 = n2 + c1s;
                    const float d2 = fmaf(49.f, vss, c2s) - n2;
                    const float den = d1 * d2;
                    float rc = __builtin_amdgcn_rcpf(den);
                    rc = rc * (2.f - den * rc);          // 1 Newton step
                    acc = fmaf(u1 * u2, rc, acc);
                }
            }
        }
    }

    // block reduction: wave shfl, then cross-wave via LDS (single barrier)
    float s = acc;
#pragma unroll
    for (int o = 32; o; o >>= 1) s += __shfl_down(s, o, 64);
    __shared__ float wsum[4];
    if (lane == 0) wsum[wid] = s;
    __syncthreads();
    if (tid == 0) {
        const int bid = (blockIdx.z * gridDim.y + blockIdx.y) * gridDim.x + blockIdx.x;
        partials[bid] = wsum[0] + wsum[1] + wsum[2] + wsum[3];
    }
}

__global__ __launch_bounds__(256)
void ssim_final(const float* __restrict__ partials, int n,
                float* __restrict__ out, float inv_count)
{
    const int tid = threadIdx.x;
    float s = 0.f;
    for (int i = tid; i < n; i += 256) s += partials[i];
#pragma unroll
    for (int o = 32; o; o >>= 1) s += __shfl_down(s, o, 64);
    __shared__ float wsum[4];
    if ((tid & 63) == 0) wsum[tid >> 6] = s;
    __syncthreads();
    if (tid == 0) out[0] = 1.0f - (wsum[0] + wsum[1] + wsum[2] + wsum[3]) * inv_count;
}

extern "C" void kernel_launch(void* const* d_in, const int* in_sizes, int n_in,
                              void* d_out, int out_size, void* d_ws, size_t ws_size,
                              hipStream_t stream)
{
    const float* X  = (const float*)d_in[0];
    const float* Y  = (const float*)d_in[1];
    const float* DR = (const float*)d_in[2];
    float* out      = (float*)d_out;
    float* partials = (float*)d_ws;

    const int gx = (OW + BW_ - 1) / BW_; // 2
    const int gy = (OH + SH - 1) / SH;   // 8
    dim3 grid(gx, gy, B);                // 1024 blocks, every partial slot written
    ssim_main<<<grid, 256, 0, stream>>>(X, Y, DR, partials);

    const int n = gx * gy * B;           // 1024
    const float inv_count = 1.0f / (float)((long)B * OH * OW);
    ssim_final<<<1, 256, 0, stream>>>(partials, n, out, inv_count);
}

// Round 26
// 46.135 us; speedup vs baseline: 1.0585x; 1.0585x over previous
//
#include <hip/hip_runtime.h>

// SSIM loss, 7x7 window, VALID, (64,1,512,512) fp32.
// R23 = R20 (champion: pk-f32 channels, read-early dual-slot, barrier-free
// wave strips) with SH 64->32: 2048 blocks = 8 blocks/CU = 32 waves/CU.
// Rationale: pk math made the kernel DS-bound (DS ~30us/CU serial vs VALU
// ~23us/SIMD; DS util only ~62% at 4 blocks/CU). DS is a per-CU shared
// pipe -> doubling resident waves fills it. Cost: +8.6% row-iters.
// f16/fdot2 retired for good (R17/R18/R22 all lost to pk-f32).

constexpr int B  = 64;
constexpr int H  = 512, W = 512;
constexpr int OH = H - 6, OW = W - 6;     // 506
constexpr int CW = 64;                    // output cols per wave
constexpr int BW_ = 4 * CW;               // output cols per block (256)
constexpr int SH = 32;                    // output rows per block

typedef float f2 __attribute__((ext_vector_type(2)));

__global__ __launch_bounds__(256)
void ssim_main(const float* __restrict__ X, const float* __restrict__ Y,
               const float* __restrict__ DR, float* __restrict__ partials)
{
    const int tid  = threadIdx.x;
    const int wid  = tid >> 6;
    const int lane = tid & 63;
    const int c0   = blockIdx.x * BW_ + wid * CW;   // wave-private strip
    const int r0   = blockIdx.y * SH;
    const int b    = blockIdx.z;

    const int out_rows = min(SH, OH - r0);
    const int rows_in  = out_rows + 6;       // <= 38, block-uniform

    const float d  = DR[b];
    const float C1 = (0.01f * d) * (0.01f * d);
    const float C2 = (0.03f * d) * (0.03f * d);
    const float c1s = 2401.0f * C1;          // 49^2 * C1
    const float c2s = 2352.0f * C2;          // 48*49 * C2

    const float* __restrict__ Xb = X + (size_t)b * H * W;
    const float* __restrict__ Yb = Y + (size_t)b * H * W;

    unsigned off  = (unsigned)(r0 * W + c0 + lane);
    unsigned hoff = (unsigned)(r0 * W + min(c0 + CW + lane, W - 1));

    const bool colvalid = (c0 + lane) < OW;
    const bool is_halo  = lane < 6;

    // wave-private DUAL-slot row buffer: {x,y} pairs, 70 used per slot
    __shared__ f2 rb[4][2][CW + 8];

    // vertical state: packed pairs P=(sx,sy), Q=(sxx,syy); scalar sxy
    f2 bP[7], bQ[7];
    float bxy[7];
    f2 P = {0.f, 0.f}, Q = {0.f, 0.f};
    float vsxy = 0.f;
#pragma unroll
    for (int i = 0; i < 7; ++i) { bP[i] = P; bQ[i] = Q; bxy[i] = 0.f; }

    float acc = 0.f;

    // prefetch pairs by parity: pre1 holds odd rows, pre0 even rows
    f2 pre0, pre1;
    f2 preh0 = {0.f, 0.f}, preh1 = {0.f, 0.f};

    // ---- prologue: row0 -> slot0 (staged), row1 -> pre1, row2 -> pre0 ----
    {
        f2 p0; p0.x = Xb[off]; p0.y = Yb[off];
        f2 ph0 = {0.f, 0.f};
        if (is_halo) { ph0.x = Xb[hoff]; ph0.y = Yb[hoff]; }
        off += W; hoff += W;
        pre1.x = Xb[off]; pre1.y = Yb[off];
        if (is_halo) { preh1.x = Xb[hoff]; preh1.y = Yb[hoff]; }
        off += W; hoff += W;
        pre0.x = Xb[off]; pre0.y = Yb[off];
        if (is_halo) { preh0.x = Xb[hoff]; preh0.y = Yb[hoff]; }
        off += W; hoff += W;

        f2* s0 = rb[wid][0];
        s0[lane] = p0;
        if (is_halo) s0[CW + lane] = ph0;
    }

    for (int rr = 0; rr < 42; rr += 14) {
#pragma unroll
        for (int p = 0; p < 14; ++p) {
            const int r = rr + p;              // r%7 == p%7, r&1 == p&1
            if (r < rows_in) {                 // block-uniform
                f2* const rslot = rb[wid][p & 1];        // row r (staged)
                f2* const wslot = rb[wid][(p & 1) ^ 1];  // row r+1 dest
                f2& pr = (p & 1) ? pre0 : pre1;          // pair(r+1)
                f2& ph = (p & 1) ? preh0 : preh1;

                // 1) issue tap reads of row r (staged last phase)
                const f2 v0 = rslot[lane+0], v1 = rslot[lane+1],
                         v2 = rslot[lane+2], v3 = rslot[lane+3],
                         v4 = rslot[lane+4], v5 = rslot[lane+5],
                         v6 = rslot[lane+6];

                // 2) stage row r+1 into the other slot
                if (r + 1 < rows_in) {
                    wslot[lane] = pr;
                    if (is_halo) wslot[CW + lane] = ph;
                    // 3) issue globals for row r+3 (same parity regs)
                    if (r + 3 < rows_in) {
                        pr.x = Xb[off]; pr.y = Yb[off];
                        if (is_halo) { ph.x = Xb[hoff]; ph.y = Yb[hoff]; }
                        off += W; hoff += W;
                    }
                }

                // 4) compute row r — packed-f32 channel math
                const f2 s2 = ((v0 + v1) + (v2 + v3)) + ((v4 + v5) + v6);
                f2 q2 = v0 * v0;
                q2 = __builtin_elementwise_fma(v1, v1, q2);
                q2 = __builtin_elementwise_fma(v2, v2, q2);
                q2 = __builtin_elementwise_fma(v3, v3, q2);
                q2 = __builtin_elementwise_fma(v4, v4, q2);
                q2 = __builtin_elementwise_fma(v5, v5, q2);
                q2 = __builtin_elementwise_fma(v6, v6, q2);
                float hxy = v0.x * v0.y;
                hxy = fmaf(v1.x, v1.y, hxy);
                hxy = fmaf(v2.x, v2.y, hxy);
                hxy = fmaf(v3.x, v3.y, hxy);
                hxy = fmaf(v4.x, v4.y, hxy);
                hxy = fmaf(v5.x, v5.y, hxy);
                hxy = fmaf(v6.x, v6.y, hxy);

                // vertical running 7-row window (slot p%7 holds row r-7)
                constexpr int s7[14] = {0,1,2,3,4,5,6,0,1,2,3,4,5,6};
                const int sp = s7[p];
                P += s2 - bP[sp];   bP[sp] = s2;     // 2 pk
                Q += q2 - bQ[sp];   bQ[sp] = q2;     // 2 pk
                vsxy += hxy - bxy[sp]; bxy[sp] = hxy;

                if (r >= 6 && colvalid) {
                    // S = (2 sx sy + c1s)(2(49 sxy - sx sy) + c2s)
                    //   / (sx^2+sy^2+c1s)(49(sxx+syy) - sx^2 - sy^2 + c2s)
                    const float vsx = P.x, vsy = P.y;
                    const float p1 = vsx * vsy;
                    const float t1 = fmaf(2.f, p1, c1s);
                    const float q  = fmaf(49.f, vsxy, -p1);
                    const float t2 = fmaf(2.f, q, c2s);
                    const float n2 = fmaf(vsy, vsy, vsx * vsx);
                    const float b1 = n2 + c1s;
                    const float s3 = Q.x + Q.y;
                    const float b2 = fmaf(49.f, s3, c2s) - n2;
                    const float num = t1 * t2;
                    const float den = b1 * b2;
                    float rcp = __builtin_amdgcn_rcpf(den);
                    rcp = rcp * (2.f - den * rcp);      // 1 Newton step
                    acc = fmaf(num, rcp, acc);
                }
            }
        }
    }

    // block reduction: wave shfl, then cross-wave via LDS (single barrier)
    float s = acc;
#pragma unroll
    for (int o = 32; o; o >>= 1) s += __shfl_down(s, o, 64);
    __shared__ float wsum[4];
    if (lane == 0) wsum[wid] = s;
    __syncthreads();
    if (tid == 0) {
        const int bid = (blockIdx.z * gridDim.y + blockIdx.y) * gridDim.x + blockIdx.x;
        partials[bid] = wsum[0] + wsum[1] + wsum[2] + wsum[3];
    }
}

__global__ __launch_bounds__(256)
void ssim_final(const float* __restrict__ partials, int n,
                float* __restrict__ out, float inv_count)
{
    const int tid = threadIdx.x;
    float s = 0.f;
    for (int i = tid; i < n; i += 256) s += partials[i];
#pragma unroll
    for (int o = 32; o; o >>= 1) s += __shfl_down(s, o, 64);
    __shared__ float wsum[4];
    if ((tid & 63) == 0) wsum[tid >> 6] = s;
    __syncthreads();
    if (tid == 0) out[0] = 1.0f - (wsum[0] + wsum[1] + wsum[2] + wsum[3]) * inv_count;
}

extern "C" void kernel_launch(void* const* d_in, const int* in_sizes, int n_in,
                              void* d_out, int out_size, void* d_ws, size_t ws_size,
                              hipStream_t stream)
{
    const float* X  = (const float*)d_in[0];
    const float* Y  = (const float*)d_in[1];
    const float* DR = (const float*)d_in[2];
    float* out      = (float*)d_out;
    float* partials = (float*)d_ws;

    const int gx = (OW + BW_ - 1) / BW_; // 2
    const int gy = (OH + SH - 1) / SH;   // 16
    dim3 grid(gx, gy, B);                // 2048 blocks, every partial slot written
    ssim_main<<<grid, 256, 0, stream>>>(X, Y, DR, partials);

    const int n = gx * gy * B;           // 2048
    const float inv_count = 1.0f / (float)((long)B * OH * OW);
    ssim_final<<<1, 256, 0, stream>>>(partials, n, out, inv_count);
}

// Round 27
// 44.118 us; speedup vs baseline: 1.1069x; 1.0457x over previous
//
#include <hip/hip_runtime.h>

// SSIM loss, 7x7 window, VALID, (64,1,512,512) fp32.
// R27: 2 output cols/lane at the 4-wave/SIMD grid where VGPR<=128 is free
// (R13's idea minus its occupancy mistake). Wave owns 128 cols; LDS entry =
// {x,y} f2 per col; lane writes its 2 cols as ONE b128, reads taps as FOUR
// ds_read_b128 -> per-col DS = 2.5 insts / 40 B (was 9 / 72): taps are
// SHARED between the lane's 2 cols, so DS bytes truly halve (unlike R21's
// pure-width merge). Col B incremental from col A (-t0 +t7). 4 channels/col.
// Keeps: pk-f32 math (R20-verified), read-early dual-slot, depth-2 parity
// prefetch, barrier-free wave-private strips, fast rcp.
// R23 lesson: occupancy is NOT grid-limited (38% at 2x blocks) -> TLP
// exhausted; this cuts DS work per pixel instead.

constexpr int B  = 64;
constexpr int H  = 512, W = 512;
constexpr int OH = H - 6, OW = W - 6;     // 506
constexpr int SH = 32;                    // output rows per block
// wave: 128 cols (2/lane); block: 4 waves = 512 cols; grid (1, 16, 64)

typedef float f2 __attribute__((ext_vector_type(2)));
typedef float f4 __attribute__((ext_vector_type(4)));

__global__ __launch_bounds__(256)
void ssim_main(const float* __restrict__ X, const float* __restrict__ Y,
               const float* __restrict__ DR, float* __restrict__ partials)
{
    const int tid  = threadIdx.x;
    const int wid  = tid >> 6;
    const int lane = tid & 63;
    const int c0   = wid * 128;             // block spans cols 0..511 (gx=1)
    const int gc   = c0 + 2 * lane;         // col A (even)
    const int r0   = blockIdx.y * SH;
    const int b    = blockIdx.z;

    const int out_rows = min(SH, OH - r0);
    const int rows_in  = out_rows + 6;       // <= 38, block-uniform

    const float d  = DR[b];
    const float C1 = (0.01f * d) * (0.01f * d);
    const float C2 = (0.03f * d) * (0.03f * d);
    const float c1s = 2401.0f * C1;          // 49^2 * C1
    const float c2s = 2352.0f * C2;          // 48*49 * C2

    const float* __restrict__ Xb = X + (size_t)b * H * W;
    const float* __restrict__ Yb = Y + (size_t)b * H * W;

    unsigned off  = (unsigned)(r0 * W + gc);
    unsigned hoff = (unsigned)(r0 * W + min(c0 + 128 + 2 * lane, W - 2));

    const bool vA = gc < OW;
    const bool vB = gc + 1 < OW;
    const bool is_halo = lane < 3;           // halo cols c0+128 .. c0+133

    // wave-private dual slots: 128 owned + 6 halo f2 entries ({x,y} per col)
    __shared__ __align__(16) f2 rb[4][2][136];

    // per-col state: P=(sx,sy) packed; ss=S(xx+yy); xy=Sxy. 7-row histories.
    f2 bPA[7], bPB[7];
    float bsA[7], bsB[7], bwA[7], bwB[7];
    f2 PA = {0.f,0.f}, PB = {0.f,0.f};
    float ssA = 0.f, ssB = 0.f, xyA = 0.f, xyB = 0.f;
#pragma unroll
    for (int i = 0; i < 7; ++i) {
        bPA[i]=PA; bPB[i]=PB; bsA[i]=0.f; bsB[i]=0.f; bwA[i]=0.f; bwB[i]=0.f;
    }

    float acc = 0.f;

    // parity prefetch (x,y col-pairs); pre1 = odd rows, pre0 = even rows
    f2 px0, py0, px1, py1;
    f2 phx0={0.f,0.f}, phy0={0.f,0.f}, phx1={0.f,0.f}, phy1={0.f,0.f};

    // ---- prologue: row0 -> slot0; row1 -> pre1; row2 -> pre0 ----
    {
        const f2 x0 = *(const f2*)(Xb + off);
        const f2 y0 = *(const f2*)(Yb + off);
        f2 hx0={0.f,0.f}, hy0={0.f,0.f};
        if (is_halo) { hx0 = *(const f2*)(Xb + hoff); hy0 = *(const f2*)(Yb + hoff); }
        off += W; hoff += W;
        px1 = *(const f2*)(Xb + off); py1 = *(const f2*)(Yb + off);
        if (is_halo) { phx1 = *(const f2*)(Xb + hoff); phy1 = *(const f2*)(Yb + hoff); }
        off += W; hoff += W;
        px0 = *(const f2*)(Xb + off); py0 = *(const f2*)(Yb + off);
        if (is_halo) { phx0 = *(const f2*)(Xb + hoff); phy0 = *(const f2*)(Yb + hoff); }
        off += W; hoff += W;

        f2* s0 = rb[wid][0];
        *(f4*)&s0[2*lane] = (f4){x0.x, y0.x, x0.y, y0.y};
        if (is_halo) *(f4*)&s0[128 + 2*lane] = (f4){hx0.x, hy0.x, hx0.y, hy0.y};
    }

    for (int rr = 0; rr < 42; rr += 14) {
#pragma unroll
        for (int p = 0; p < 14; ++p) {
            const int r = rr + p;              // r%7 == p%7, r&1 == p&1
            if (r < rows_in) {                 // block-uniform
                f2* const rslot = rb[wid][p & 1];        // row r (staged)
                f2* const wslot = rb[wid][(p & 1) ^ 1];  // row r+1 dest
                f2& px = (p & 1) ? px0 : px1;            // pair(r+1)
                f2& py = (p & 1) ? py0 : py1;
                f2& phx = (p & 1) ? phx0 : phx1;
                f2& phy = (p & 1) ? phy0 : phy1;

                // 1) tap reads: 4x ds_read_b128 -> cols gc..gc+7
                const f4 q0 = *(const f4*)&rslot[2*lane + 0];
                const f4 q1 = *(const f4*)&rslot[2*lane + 2];
                const f4 q2 = *(const f4*)&rslot[2*lane + 4];
                const f4 q3 = *(const f4*)&rslot[2*lane + 6];

                // 2) stage row r+1 (one b128 + halo); 3) prefetch row r+3
                if (r + 1 < rows_in) {
                    *(f4*)&wslot[2*lane] = (f4){px.x, py.x, px.y, py.y};
                    if (is_halo)
                        *(f4*)&wslot[128 + 2*lane] = (f4){phx.x, phy.x, phx.y, phy.y};
                    if (r + 3 < rows_in) {
                        px = *(const f2*)(Xb + off);
                        py = *(const f2*)(Yb + off);
                        if (is_halo) { phx = *(const f2*)(Xb + hoff);
                                       phy = *(const f2*)(Yb + hoff); }
                        off += W; hoff += W;
                    }
                }

                // 4) compute cols A (taps 0-6) and B (incremental, taps 1-7)
                const f2 t0={q0.x,q0.y}, t1={q0.z,q0.w},
                         t2={q1.x,q1.y}, t3={q1.z,q1.w},
                         t4={q2.x,q2.y}, t5={q2.z,q2.w},
                         t6={q3.x,q3.y}, t7={q3.z,q3.w};

                const f2 s2A = ((t0+t1)+(t2+t3)) + ((t4+t5)+t6);
                const f2 s2B = (s2A - t0) + t7;
                const f2 tsq0 = t0*t0, tsq7 = t7*t7;
                f2 q2A = tsq0;
                q2A = __builtin_elementwise_fma(t1,t1,q2A);
                q2A = __builtin_elementwise_fma(t2,t2,q2A);
                q2A = __builtin_elementwise_fma(t3,t3,q2A);
                q2A = __builtin_elementwise_fma(t4,t4,q2A);
                q2A = __builtin_elementwise_fma(t5,t5,q2A);
                q2A = __builtin_elementwise_fma(t6,t6,q2A);
                const f2 q2B = (q2A - tsq0) + tsq7;
                const float hsA = q2A.x + q2A.y;
                const float hsB = q2B.x + q2B.y;
                const float t0xy = t0.x * t0.y;
                float hxyA = t0xy;
                hxyA = fmaf(t1.x,t1.y,hxyA); hxyA = fmaf(t2.x,t2.y,hxyA);
                hxyA = fmaf(t3.x,t3.y,hxyA); hxyA = fmaf(t4.x,t4.y,hxyA);
                hxyA = fmaf(t5.x,t5.y,hxyA); hxyA = fmaf(t6.x,t6.y,hxyA);
                const float hxyB = fmaf(t7.x, t7.y, hxyA - t0xy);

                // vertical running 7-row window (slot p%7 holds row r-7)
                constexpr int s7[14] = {0,1,2,3,4,5,6,0,1,2,3,4,5,6};
                const int sp = s7[p];
                PA  += s2A  - bPA[sp]; bPA[sp] = s2A;
                ssA += hsA  - bsA[sp]; bsA[sp] = hsA;
                xyA += hxyA - bwA[sp]; bwA[sp] = hxyA;
                PB  += s2B  - bPB[sp]; bPB[sp] = s2B;
                ssB += hsB  - bsB[sp]; bsB[sp] = hsB;
                xyB += hxyB - bwB[sp]; bwB[sp] = hxyB;

                if (r >= 6) {
                    // S = (2 SxSy + c1s)(2(49 Sxy - SxSy) + c2s)
                    //   / (Sx^2+Sy^2+c1s)(49 ss - Sx^2 - Sy^2 + c2s)
                    {   const float p1 = PA.x * PA.y;
                        const float u1 = fmaf(2.f, p1, c1s);
                        const float qv = fmaf(49.f, xyA, -p1);
                        const float u2 = fmaf(2.f, qv, c2s);
                        const float n2 = fmaf(PA.y, PA.y, PA.x * PA.x);
                        const float d1 = n2 + c1s;
                        const float d2 = fmaf(49.f, ssA, c2s) - n2;
                        const float den = d1 * d2;
                        float rc = __builtin_amdgcn_rcpf(den);
                        rc = rc * (2.f - den * rc);
                        acc += vA ? (u1 * u2) * rc : 0.f;
                    }
                    {   const float p1 = PB.x * PB.y;
                        const float u1 = fmaf(2.f, p1, c1s);
                        const float qv = fmaf(49.f, xyB, -p1);
                        const float u2 = fmaf(2.f, qv, c2s);
                        const float n2 = fmaf(PB.y, PB.y, PB.x * PB.x);
                        const float d1 = n2 + c1s;
                        const float d2 = fmaf(49.f, ssB, c2s) - n2;
                        const float den = d1 * d2;
                        float rc = __builtin_amdgcn_rcpf(den);
                        rc = rc * (2.f - den * rc);
                        acc += vB ? (u1 * u2) * rc : 0.f;
                    }
                }
            }
        }
    }

    // block reduction: wave shfl, then cross-wave via LDS (single barrier)
    float s = acc;
#pragma unroll
    for (int o = 32; o; o >>= 1) s += __shfl_down(s, o, 64);
    __shared__ float wsum[4];
    if (lane == 0) wsum[wid] = s;
    __syncthreads();
    if (tid == 0) {
        const int bid = blockIdx.z * gridDim.y + blockIdx.y;
        partials[bid] = wsum[0] + wsum[1] + wsum[2] + wsum[3];
    }
}

__global__ __launch_bounds__(256)
void ssim_final(const float* __restrict__ partials, int n,
                float* __restrict__ out, float inv_count)
{
    const int tid = threadIdx.x;
    float s = 0.f;
    for (int i = tid; i < n; i += 256) s += partials[i];
#pragma unroll
    for (int o = 32; o; o >>= 1) s += __shfl_down(s, o, 64);
    __shared__ float wsum[4];
    if ((tid & 63) == 0) wsum[tid >> 6] = s;
    __syncthreads();
    if (tid == 0) out[0] = 1.0f - (wsum[0] + wsum[1] + wsum[2] + wsum[3]) * inv_count;
}

extern "C" void kernel_launch(void* const* d_in, const int* in_sizes, int n_in,
                              void* d_out, int out_size, void* d_ws, size_t ws_size,
                              hipStream_t stream)
{
    const float* X  = (const float*)d_in[0];
    const float* Y  = (const float*)d_in[1];
    const float* DR = (const float*)d_in[2];
    float* out      = (float*)d_out;
    float* partials = (float*)d_ws;

    const int gy = (OH + SH - 1) / SH;   // 16
    dim3 grid(1, gy, B);                 // 1024 blocks, every partial slot written
    ssim_main<<<grid, 256, 0, stream>>>(X, Y, DR, partials);

    const int n = gy * B;                // 1024
    const float inv_count = 1.0f / (float)((long)B * OH * OW);
    ssim_final<<<1, 256, 0, stream>>>(partials, n, out, inv_count);
}

// Round 28
// 42.887 us; speedup vs baseline: 1.1387x; 1.0287x over previous
//
#include <hip/hip_runtime.h>

// SSIM loss, 7x7 window, VALID, (64,1,512,512) fp32.
// R28 = R27 (2 cols/lane, shared-tap b128 reads, incremental col B, pk-f32)
// with SH 32->64: warm-up rows drop from 6/38=16% to 6/70=8.6% of iters
// (-7.9% total wave-iters). R27 proved this structure tolerates low
// occupancy (21% and still 44.1us), so halving blocks (512, 2/CU) should
// cost little. Single-knob A/B on strip height for the 2-col champion.

constexpr int B  = 64;
constexpr int H  = 512, W = 512;
constexpr int OH = H - 6, OW = W - 6;     // 506
constexpr int SH = 64;                    // output rows per block
// wave: 128 cols (2/lane); block: 4 waves = 512 cols; grid (1, 8, 64)

typedef float f2 __attribute__((ext_vector_type(2)));
typedef float f4 __attribute__((ext_vector_type(4)));

__global__ __launch_bounds__(256)
void ssim_main(const float* __restrict__ X, const float* __restrict__ Y,
               const float* __restrict__ DR, float* __restrict__ partials)
{
    const int tid  = threadIdx.x;
    const int wid  = tid >> 6;
    const int lane = tid & 63;
    const int c0   = wid * 128;             // block spans cols 0..511 (gx=1)
    const int gc   = c0 + 2 * lane;         // col A (even)
    const int r0   = blockIdx.y * SH;
    const int b    = blockIdx.z;

    const int out_rows = min(SH, OH - r0);
    const int rows_in  = out_rows + 6;       // 70, or 64 on last strip (even)

    const float d  = DR[b];
    const float C1 = (0.01f * d) * (0.01f * d);
    const float C2 = (0.03f * d) * (0.03f * d);
    const float c1s = 2401.0f * C1;          // 49^2 * C1
    const float c2s = 2352.0f * C2;          // 48*49 * C2

    const float* __restrict__ Xb = X + (size_t)b * H * W;
    const float* __restrict__ Yb = Y + (size_t)b * H * W;

    unsigned off  = (unsigned)(r0 * W + gc);
    unsigned hoff = (unsigned)(r0 * W + min(c0 + 128 + 2 * lane, W - 2));

    const bool vA = gc < OW;
    const bool vB = gc + 1 < OW;
    const bool is_halo = lane < 3;           // halo cols c0+128 .. c0+133

    // wave-private dual slots: 128 owned + 6 halo f2 entries ({x,y} per col)
    __shared__ __align__(16) f2 rb[4][2][136];

    // per-col state: P=(sx,sy) packed; ss=S(xx+yy); xy=Sxy. 7-row histories.
    f2 bPA[7], bPB[7];
    float bsA[7], bsB[7], bwA[7], bwB[7];
    f2 PA = {0.f,0.f}, PB = {0.f,0.f};
    float ssA = 0.f, ssB = 0.f, xyA = 0.f, xyB = 0.f;
#pragma unroll
    for (int i = 0; i < 7; ++i) {
        bPA[i]=PA; bPB[i]=PB; bsA[i]=0.f; bsB[i]=0.f; bwA[i]=0.f; bwB[i]=0.f;
    }

    float acc = 0.f;

    // parity prefetch (x,y col-pairs); pre1 = odd rows, pre0 = even rows
    f2 px0, py0, px1, py1;
    f2 phx0={0.f,0.f}, phy0={0.f,0.f}, phx1={0.f,0.f}, phy1={0.f,0.f};

    // ---- prologue: row0 -> slot0; row1 -> pre1; row2 -> pre0 ----
    {
        const f2 x0 = *(const f2*)(Xb + off);
        const f2 y0 = *(const f2*)(Yb + off);
        f2 hx0={0.f,0.f}, hy0={0.f,0.f};
        if (is_halo) { hx0 = *(const f2*)(Xb + hoff); hy0 = *(const f2*)(Yb + hoff); }
        off += W; hoff += W;
        px1 = *(const f2*)(Xb + off); py1 = *(const f2*)(Yb + off);
        if (is_halo) { phx1 = *(const f2*)(Xb + hoff); phy1 = *(const f2*)(Yb + hoff); }
        off += W; hoff += W;
        px0 = *(const f2*)(Xb + off); py0 = *(const f2*)(Yb + off);
        if (is_halo) { phx0 = *(const f2*)(Xb + hoff); phy0 = *(const f2*)(Yb + hoff); }
        off += W; hoff += W;

        f2* s0 = rb[wid][0];
        *(f4*)&s0[2*lane] = (f4){x0.x, y0.x, x0.y, y0.y};
        if (is_halo) *(f4*)&s0[128 + 2*lane] = (f4){hx0.x, hy0.x, hx0.y, hy0.y};
    }

    for (int rr = 0; rr < 70; rr += 14) {
#pragma unroll
        for (int p = 0; p < 14; ++p) {
            const int r = rr + p;              // r%7 == p%7, r&1 == p&1
            if (r < rows_in) {                 // block-uniform
                f2* const rslot = rb[wid][p & 1];        // row r (staged)
                f2* const wslot = rb[wid][(p & 1) ^ 1];  // row r+1 dest
                f2& px = (p & 1) ? px0 : px1;            // pair(r+1)
                f2& py = (p & 1) ? py0 : py1;
                f2& phx = (p & 1) ? phx0 : phx1;
                f2& phy = (p & 1) ? phy0 : phy1;

                // 1) tap reads: 4x ds_read_b128 -> cols gc..gc+7
                const f4 q0 = *(const f4*)&rslot[2*lane + 0];
                const f4 q1 = *(const f4*)&rslot[2*lane + 2];
                const f4 q2 = *(const f4*)&rslot[2*lane + 4];
                const f4 q3 = *(const f4*)&rslot[2*lane + 6];

                // 2) stage row r+1 (one b128 + halo); 3) prefetch row r+3
                if (r + 1 < rows_in) {
                    *(f4*)&wslot[2*lane] = (f4){px.x, py.x, px.y, py.y};
                    if (is_halo)
                        *(f4*)&wslot[128 + 2*lane] = (f4){phx.x, phy.x, phx.y, phy.y};
                    if (r + 3 < rows_in) {
                        px = *(const f2*)(Xb + off);
                        py = *(const f2*)(Yb + off);
                        if (is_halo) { phx = *(const f2*)(Xb + hoff);
                                       phy = *(const f2*)(Yb + hoff); }
                        off += W; hoff += W;
                    }
                }

                // 4) compute cols A (taps 0-6) and B (incremental, taps 1-7)
                const f2 t0={q0.x,q0.y}, t1={q0.z,q0.w},
                         t2={q1.x,q1.y}, t3={q1.z,q1.w},
                         t4={q2.x,q2.y}, t5={q2.z,q2.w},
                         t6={q3.x,q3.y}, t7={q3.z,q3.w};

                const f2 s2A = ((t0+t1)+(t2+t3)) + ((t4+t5)+t6);
                const f2 s2B = (s2A - t0) + t7;
                const f2 tsq0 = t0*t0, tsq7 = t7*t7;
                f2 q2A = tsq0;
                q2A = __builtin_elementwise_fma(t1,t1,q2A);
                q2A = __builtin_elementwise_fma(t2,t2,q2A);
                q2A = __builtin_elementwise_fma(t3,t3,q2A);
                q2A = __builtin_elementwise_fma(t4,t4,q2A);
                q2A = __builtin_elementwise_fma(t5,t5,q2A);
                q2A = __builtin_elementwise_fma(t6,t6,q2A);
                const f2 q2B = (q2A - tsq0) + tsq7;
                const float hsA = q2A.x + q2A.y;
                const float hsB = q2B.x + q2B.y;
                const float t0xy = t0.x * t0.y;
                float hxyA = t0xy;
                hxyA = fmaf(t1.x,t1.y,hxyA); hxyA = fmaf(t2.x,t2.y,hxyA);
                hxyA = fmaf(t3.x,t3.y,hxyA); hxyA = fmaf(t4.x,t4.y,hxyA);
                hxyA = fmaf(t5.x,t5.y,hxyA); hxyA = fmaf(t6.x,t6.y,hxyA);
                const float hxyB = fmaf(t7.x, t7.y, hxyA - t0xy);

                // vertical running 7-row window (slot p%7 holds row r-7)
                constexpr int s7[14] = {0,1,2,3,4,5,6,0,1,2,3,4,5,6};
                const int sp = s7[p];
                PA  += s2A  - bPA[sp]; bPA[sp] = s2A;
                ssA += hsA  - bsA[sp]; bsA[sp] = hsA;
                xyA += hxyA - bwA[sp]; bwA[sp] = hxyA;
                PB  += s2B  - bPB[sp]; bPB[sp] = s2B;
                ssB += hsB  - bsB[sp]; bsB[sp] = hsB;
                xyB += hxyB - bwB[sp]; bwB[sp] = hxyB;

                if (r >= 6) {
                    // S = (2 SxSy + c1s)(2(49 Sxy - SxSy) + c2s)
                    //   / (Sx^2+Sy^2+c1s)(49 ss - Sx^2 - Sy^2 + c2s)
                    {   const float p1 = PA.x * PA.y;
                        const float u1 = fmaf(2.f, p1, c1s);
                        const float qv = fmaf(49.f, xyA, -p1);
                        const float u2 = fmaf(2.f, qv, c2s);
                        const float n2 = fmaf(PA.y, PA.y, PA.x * PA.x);
                        const float d1 = n2 + c1s;
                        const float d2 = fmaf(49.f, ssA, c2s) - n2;
                        const float den = d1 * d2;
                        float rc = __builtin_amdgcn_rcpf(den);
                        rc = rc * (2.f - den * rc);
                        acc += vA ? (u1 * u2) * rc : 0.f;
                    }
                    {   const float p1 = PB.x * PB.y;
                        const float u1 = fmaf(2.f, p1, c1s);
                        const float qv = fmaf(49.f, xyB, -p1);
                        const float u2 = fmaf(2.f, qv, c2s);
                        const float n2 = fmaf(PB.y, PB.y, PB.x * PB.x);
                        const float d1 = n2 + c1s;
                        const float d2 = fmaf(49.f, ssB, c2s) - n2;
                        const float den = d1 * d2;
                        float rc = __builtin_amdgcn_rcpf(den);
                        rc = rc * (2.f - den * rc);
                        acc += vB ? (u1 * u2) * rc : 0.f;
                    }
                }
            }
        }
    }

    // block reduction: wave shfl, then cross-wave via LDS (single barrier)
    float s = acc;
#pragma unroll
    for (int o = 32; o; o >>= 1) s += __shfl_down(s, o, 64);
    __shared__ float wsum[4];
    if (lane == 0) wsum[wid] = s;
    __syncthreads();
    if (tid == 0) {
        const int bid = blockIdx.z * gridDim.y + blockIdx.y;
        partials[bid] = wsum[0] + wsum[1] + wsum[2] + wsum[3];
    }
}

__global__ __launch_bounds__(256)
void ssim_final(const float* __restrict__ partials, int n,
                float* __restrict__ out, float inv_count)
{
    const int tid = threadIdx.x;
    float s = 0.f;
    for (int i = tid; i < n; i += 256) s += partials[i];
#pragma unroll
    for (int o = 32; o; o >>= 1) s += __shfl_down(s, o, 64);
    __shared__ float wsum[4];
    if ((tid & 63) == 0) wsum[tid >> 6] = s;
    __syncthreads();
    if (tid == 0) out[0] = 1.0f - (wsum[0] + wsum[1] + wsum[2] + wsum[3]) * inv_count;
}

extern "C" void kernel_launch(void* const* d_in, const int* in_sizes, int n_in,
                              void* d_out, int out_size, void* d_ws, size_t ws_size,
                              hipStream_t stream)
{
    const float* X  = (const float*)d_in[0];
    const float* Y  = (const float*)d_in[1];
    const float* DR = (const float*)d_in[2];
    float* out      = (float*)d_out;
    float* partials = (float*)d_ws;

    const int gy = (OH + SH - 1) / SH;   // 8
    dim3 grid(1, gy, B);                 // 512 blocks, every partial slot written
    ssim_main<<<grid, 256, 0, stream>>>(X, Y, DR, partials);

    const int n = gy * B;                // 512
    const float inv_count = 1.0f / (float)((long)B * OH * OW);
    ssim_final<<<1, 256, 0, stream>>>(partials, n, out, inv_count);
}